// Round 2
// baseline (606.315 us; speedup 1.0000x reference)
//
#include <hip/hip_runtime.h>

// Problem constants
#define B_    4
#define T_    2048
#define C_    1024
#define DATTN 1024
#define NHEAD 16
#define M_    (B_*T_)       // 8192 rows
#define NQKV  (3*DATTN)     // 3072

typedef __bf16 bf16;
typedef bf16  bf16x8 __attribute__((ext_vector_type(8)));
typedef float f32x4  __attribute__((ext_vector_type(4)));

#define NEGBIG (-1e30f)

// ---------------------------------------------------------------------------
// External-dtype helpers.  The harness may hand us bf16 or fp32 buffers; we
// detect at runtime (see detect_dtype) and instantiate both paths.
// ---------------------------------------------------------------------------
template<typename T> struct Ext;
template<> struct Ext<bf16> {
    static constexpr int want = 0;
    static __device__ __forceinline__ bf16x8 load8(const bf16* p) { return *(const bf16x8*)p; }
    static __device__ __forceinline__ float  ld(const bf16* p)    { return (float)*p; }
    static __device__ __forceinline__ void   st(bf16* p, float v) { *p = (bf16)v; }
};
template<> struct Ext<float> {
    static constexpr int want = 1;
    static __device__ __forceinline__ bf16x8 load8(const float* p) {
        f32x4 a = *(const f32x4*)p, b = *(const f32x4*)(p + 4);
        bf16x8 r;
        r[0] = (bf16)a[0]; r[1] = (bf16)a[1]; r[2] = (bf16)a[2]; r[3] = (bf16)a[3];
        r[4] = (bf16)b[0]; r[5] = (bf16)b[1]; r[6] = (bf16)b[2]; r[7] = (bf16)b[3];
        return r;
    }
    static __device__ __forceinline__ float ld(const float* p)   { return *p; }
    static __device__ __forceinline__ void  st(float* p, float v){ *p = v; }
};

// ---------------------------------------------------------------------------
// Dtype detector: view x as uint16; bf16 N(0,1) data never has exponent 0xFF,
// fp32 data's low mantissa halves hit it ~1/256.  flag: 0 = bf16, 1 = fp32.
// ---------------------------------------------------------------------------
__global__ void detect_dtype(const unsigned short* __restrict__ x, int n, int* flag) {
    __shared__ int cnt;
    if (threadIdx.x == 0) cnt = 0;
    __syncthreads();
    int local = 0;
    for (int i = threadIdx.x; i < n; i += 256)
        if (((x[i] >> 7) & 0xFF) == 0xFF) ++local;
    atomicAdd(&cnt, local);
    __syncthreads();
    if (threadIdx.x == 0) *flag = (cnt > 0) ? 1 : 0;
}

// ---------------------------------------------------------------------------
// Transpose: dst[c][r] = (bf16)src[r][c].  R, C multiples of 32.
// ---------------------------------------------------------------------------
template<typename T>
__global__ void transpose_to_bf16(const T* __restrict__ src, bf16* __restrict__ dst,
                                  int R, int C, const int* __restrict__ flag) {
    if (*flag != Ext<T>::want) return;
    __shared__ bf16 tile[32][33];
    const int c0 = blockIdx.x * 32, r0 = blockIdx.y * 32;
    const int tx = threadIdx.x & 31, ty = threadIdx.x >> 5;   // 32 x 8
    for (int p = 0; p < 4; ++p) {
        int row = p * 8 + ty;
        tile[row][tx] = (bf16)Ext<T>::ld(&src[(size_t)(r0 + row) * C + c0 + tx]);
    }
    __syncthreads();
    for (int p = 0; p < 4; ++p) {
        int row = p * 8 + ty;
        dst[(size_t)(c0 + row) * R + r0 + tx] = tile[tx][row];
    }
}

// ---------------------------------------------------------------------------
// GEMM: C[M,N] = A[M,K] * Bt[N,K]^T + bias[N]; fp32 accumulate.
// 128x128 tile, BK=64, 256 threads = 4 waves (2x2 of 64x64), 16x16x32 MFMA.
// TA = dtype of A, TB of bias, TC of C.  Bt is always bf16 (workspace).
// ---------------------------------------------------------------------------
template<typename TA, typename TB, typename TC>
__global__ __launch_bounds__(256) void gemm_bt(const TA* __restrict__ A,
                                               const bf16* __restrict__ Bt,
                                               const TB* __restrict__ bias,
                                               TC* __restrict__ Cc,
                                               int M, int N, int K,
                                               const int* __restrict__ flag, int want) {
    if (*flag != want) return;
    __shared__ __align__(16) bf16 As[128 * 72];   // row stride 72 (pad 64->72)
    __shared__ __align__(16) bf16 Bs[128 * 72];
    const int tid  = threadIdx.x;
    const int lane = tid & 63, wave = tid >> 6;
    const int quad = lane >> 4, l15 = lane & 15;
    const int wr = wave >> 1, wc = wave & 1;
    const int m0 = blockIdx.y * 128, n0 = blockIdx.x * 128;

    f32x4 acc[4][4];
    for (int i = 0; i < 4; ++i)
        for (int j = 0; j < 4; ++j)
            acc[i][j] = f32x4{0.f, 0.f, 0.f, 0.f};

    for (int k0 = 0; k0 < K; k0 += 64) {
        for (int p = 0; p < 4; ++p) {
            int idx = p * 256 + tid;
            int row = idx >> 3, col8 = (idx & 7) * 8;
            *(bf16x8*)&As[row * 72 + col8] =
                Ext<TA>::load8(&A[(size_t)(m0 + row) * K + k0 + col8]);
            *(bf16x8*)&Bs[row * 72 + col8] =
                *(const bf16x8*)&Bt[(size_t)(n0 + row) * K + k0 + col8];
        }
        __syncthreads();
        for (int ks = 0; ks < 2; ++ks) {
            bf16x8 af[4], bfr[4];
            for (int i = 0; i < 4; ++i)
                af[i] = *(const bf16x8*)&As[(wr * 64 + i * 16 + l15) * 72 + ks * 32 + quad * 8];
            for (int j = 0; j < 4; ++j)
                bfr[j] = *(const bf16x8*)&Bs[(wc * 64 + j * 16 + l15) * 72 + ks * 32 + quad * 8];
            for (int i = 0; i < 4; ++i)
                for (int j = 0; j < 4; ++j)
                    acc[i][j] = __builtin_amdgcn_mfma_f32_16x16x32_bf16(af[i], bfr[j], acc[i][j], 0, 0, 0);
        }
        __syncthreads();
    }

    // epilogue: C/D layout col=lane&15, row=quad*4+reg
    for (int i = 0; i < 4; ++i) {
        int row = m0 + wr * 64 + i * 16 + quad * 4;
        for (int j = 0; j < 4; ++j) {
            int col = n0 + wc * 64 + j * 16 + l15;
            float bv = Ext<TB>::ld(&bias[col]);
            for (int r = 0; r < 4; ++r)
                Ext<TC>::st(&Cc[(size_t)(row + r) * N + col], acc[i][j][r] + bv);
        }
    }
}

// ---------------------------------------------------------------------------
// Flash attention, causal.  qkv[B*T, 3072] bf16 (workspace).  One block =
// one (b, h, 64-row Q tile); 4 waves, each wave owns 16 q-rows.  Online
// softmax with finite mask constants (no inf arithmetic anywhere).
// ---------------------------------------------------------------------------
__global__ __launch_bounds__(256) void attn_fused(const bf16* __restrict__ qkv,
                                                  bf16* __restrict__ out) {
    __shared__ __align__(16) bf16 Ks[64 * 72];      // [key][head]
    __shared__ __align__(16) bf16 Vt[64 * 72];      // [head][key] (transposed)
    __shared__ __align__(16) bf16 Ps[4 * 16 * 72];  // per-wave P [16 q][64 key]
    const int tid  = threadIdx.x;
    const int lane = tid & 63, wave = tid >> 6;
    const int quad = lane >> 4, l15 = lane & 15;
    const int qt = blockIdx.x & 31;           // T/64 = 32 q-tiles
    const int h  = (blockIdx.x >> 5) & 15;
    const int b  = blockIdx.x >> 9;
    const int q0 = qt * 64;
    const size_t rowbase = (size_t)b * T_;

    // Q fragments (A-layout: m=lane&15, k=quad*8+j)
    bf16x8 qf[2];
    {
        size_t r = rowbase + q0 + wave * 16 + l15;
        const bf16* p = &qkv[r * NQKV + h * 64];
        qf[0] = *(const bf16x8*)&p[quad * 8];
        qf[1] = *(const bf16x8*)&p[32 + quad * 8];
    }

    f32x4 oa[4];
    for (int c = 0; c < 4; ++c) oa[c] = f32x4{0.f, 0.f, 0.f, 0.f};
    float mrow[4], lrow[4];
    for (int r = 0; r < 4; ++r) { mrow[r] = NEGBIG; lrow[r] = 0.f; }
    bf16* Pw = &Ps[wave * 16 * 72];

    for (int kt = 0; kt <= qt; ++kt) {
        const int k0 = kt * 64;
        __syncthreads();   // protect Ks/Vt from previous iteration's readers
        for (int p = 0; p < 2; ++p) {
            int idx = p * 256 + tid;
            int row = idx >> 3, col8 = (idx & 7) * 8;
            size_t gr = (rowbase + k0 + row) * (size_t)NQKV + h * 64 + col8;
            *(bf16x8*)&Ks[row * 72 + col8] = *(const bf16x8*)&qkv[DATTN + gr];
            bf16x8 v = *(const bf16x8*)&qkv[2 * DATTN + gr];
            for (int jj = 0; jj < 8; ++jj) Vt[(col8 + jj) * 72 + row] = v[jj];
        }
        __syncthreads();

        // S = Q * K^T  (16 q-rows x 64 keys per wave)
        f32x4 sc[4];
        for (int c = 0; c < 4; ++c) sc[c] = f32x4{0.f, 0.f, 0.f, 0.f};
        for (int ks = 0; ks < 2; ++ks)
            for (int c = 0; c < 4; ++c) {
                bf16x8 kf = *(const bf16x8*)&Ks[(c * 16 + l15) * 72 + ks * 32 + quad * 8];
                sc[c] = __builtin_amdgcn_mfma_f32_16x16x32_bf16(qf[ks], kf, sc[c], 0, 0, 0);
            }

        // scale + causal mask; C-layout: col=lane&15 (key), row=quad*4+r (q)
        float s[4][4];
        const bool diag = (kt == qt);
        for (int c = 0; c < 4; ++c) {
            int key = k0 + c * 16 + l15;
            for (int r = 0; r < 4; ++r) {
                float v = sc[c][r] * 0.125f;   // 1/sqrt(64)
                if (diag) {
                    int q = q0 + wave * 16 + quad * 4 + r;
                    if (key > q) v = NEGBIG;
                }
                s[c][r] = v;
            }
        }
        // online softmax: row reductions across the 16 lanes of the quad
        float alpha[4];
        for (int r = 0; r < 4; ++r) {
            float v = fmaxf(fmaxf(s[0][r], s[1][r]), fmaxf(s[2][r], s[3][r]));
            for (int off = 1; off < 16; off <<= 1) v = fmaxf(v, __shfl_xor(v, off));
            float mnew = fmaxf(mrow[r], v);
            alpha[r] = __expf(mrow[r] - mnew);   // exp(-huge) underflows to 0
            mrow[r] = mnew;
        }
        float rs[4] = {0.f, 0.f, 0.f, 0.f};
        for (int c = 0; c < 4; ++c)
            for (int r = 0; r < 4; ++r) {
                float p = __expf(s[c][r] - mrow[r]);
                rs[r] += p;
                Pw[(quad * 4 + r) * 72 + c * 16 + l15] = (bf16)p;
            }
        for (int r = 0; r < 4; ++r) {
            float v = rs[r];
            for (int off = 1; off < 16; off <<= 1) v += __shfl_xor(v, off);
            lrow[r] = lrow[r] * alpha[r] + v;
        }
        for (int c = 0; c < 4; ++c)
            for (int r = 0; r < 4; ++r) oa[c][r] *= alpha[r];

        // PV: P A-frags from LDS (within-wave write->read), V B-frags from Vt
        for (int ks2 = 0; ks2 < 2; ++ks2) {
            bf16x8 pf = *(const bf16x8*)&Pw[l15 * 72 + ks2 * 32 + quad * 8];
            for (int c2 = 0; c2 < 4; ++c2) {
                bf16x8 vf = *(const bf16x8*)&Vt[(c2 * 16 + l15) * 72 + ks2 * 32 + quad * 8];
                oa[c2] = __builtin_amdgcn_mfma_f32_16x16x32_bf16(pf, vf, oa[c2], 0, 0, 0);
            }
        }
    }

    // normalize and store: out[b*T + q][h*64 + d]
    {
        size_t r0 = rowbase + q0 + wave * 16 + quad * 4;
        for (int c2 = 0; c2 < 4; ++c2) {
            int col = h * 64 + c2 * 16 + l15;
            for (int r = 0; r < 4; ++r)
                out[(r0 + r) * (size_t)DATTN + col] = (bf16)(oa[c2][r] / lrow[r]);
        }
    }
}

// ---------------------------------------------------------------------------
// Launch: detect dtype -> transpose weights -> QKV GEMM -> attention -> out GEMM
// Both dtype variants of each external-facing kernel launch; the flag gates
// which one does work (uniform early-return; graph-capture safe).
// ---------------------------------------------------------------------------
extern "C" void kernel_launch(void* const* d_in, const int* in_sizes, int n_in,
                              void* d_out, int out_size, void* d_ws, size_t ws_size,
                              hipStream_t stream) {
    const void* x     = d_in[0];
    // d_in[1] = mask (int32 tril) — causal semantics hardcoded
    const void* W_qkv = d_in[2];
    const void* b_qkv = d_in[3];
    const void* W_out = d_in[4];
    const void* b_out = d_in[5];

    char* ws = (char*)d_ws;
    int*  flag    = (int*)ws;
    bf16* qkv_buf = (bf16*)(ws + 256);                                  // 50331648 B
    bf16* Wqkv_t  = (bf16*)(ws + 256 + 50331648);                       // 6291456 B
    bf16* Wout_t  = (bf16*)(ws + 256 + 50331648 + 6291456);             // 2097152 B
    bf16* att_buf = (bf16*)(ws + 256 + 50331648 + 6291456 + 2097152);   // 16777216 B

    // 0. detect external dtype (0 = bf16, 1 = fp32)
    detect_dtype<<<1, 256, 0, stream>>>((const unsigned short*)x, 65536, flag);

    // 1. transpose weights to B^T layout (both dtype variants; one no-ops)
    transpose_to_bf16<bf16 ><<<dim3(NQKV / 32, C_ / 32), 256, 0, stream>>>((const bf16*)W_qkv, Wqkv_t, C_, NQKV, flag);
    transpose_to_bf16<float><<<dim3(NQKV / 32, C_ / 32), 256, 0, stream>>>((const float*)W_qkv, Wqkv_t, C_, NQKV, flag);
    transpose_to_bf16<bf16 ><<<dim3(C_ / 32, DATTN / 32), 256, 0, stream>>>((const bf16*)W_out, Wout_t, DATTN, C_, flag);
    transpose_to_bf16<float><<<dim3(C_ / 32, DATTN / 32), 256, 0, stream>>>((const float*)W_out, Wout_t, DATTN, C_, flag);

    // 2. QKV projection: [8192,1024] x [1024,3072] + b_qkv -> bf16 ws
    gemm_bt<bf16, bf16, bf16><<<dim3(NQKV / 128, M_ / 128), 256, 0, stream>>>(
        (const bf16*)x, Wqkv_t, (const bf16*)b_qkv, qkv_buf, M_, NQKV, C_, flag, 0);
    gemm_bt<float, float, bf16><<<dim3(NQKV / 128, M_ / 128), 256, 0, stream>>>(
        (const float*)x, Wqkv_t, (const float*)b_qkv, qkv_buf, M_, NQKV, C_, flag, 1);

    // 3. causal flash attention (pure workspace bf16; dtype-agnostic)
    attn_fused<<<dim3(B_ * NHEAD * (T_ / 64)), 256, 0, stream>>>(qkv_buf, att_buf);

    // 4. output projection: [8192,1024] x [1024,1024] + b_out -> d_out
    gemm_bt<bf16, bf16, bf16><<<dim3(C_ / 128, M_ / 128), 256, 0, stream>>>(
        att_buf, Wout_t, (const bf16*)b_out, (bf16*)d_out, M_, C_, DATTN, flag, 0);
    gemm_bt<bf16, float, float><<<dim3(C_ / 128, M_ / 128), 256, 0, stream>>>(
        att_buf, Wout_t, (const float*)b_out, (float*)d_out, M_, C_, DATTN, flag, 1);
}